// Round 11
// baseline (25.255 us; speedup 1.0000x reference)
//
#include <hip/hip_runtime.h>
#include <math.h>

#define MU 1e-4f
#define COUNT_EPS 1e-4f
#define TWO_PI_F 6.28318530717958647692f
#define PI_F 3.14159265358979323846f
#define HALF_PI_F 1.57079632679489661923f

constexpr int P   = 8;    // partitions (reference fixes 8)
constexpr int N   = 128;  // neighbors
constexpr int WPB = 4;    // waves per block; 1 row per wave (max TLP)

// native vector type so __builtin_nontemporal_load/store accept it
typedef float f4 __attribute__((ext_vector_type(4)));

__device__ __forceinline__ f4 ldnt(const f4* p) {
    return __builtin_nontemporal_load(p);
}

// ---- DPP wave-64 sum: result valid in lane 63 (rocPRIM idiom) ----
template <int CTRL>
__device__ __forceinline__ float dpp_add(float v) {
    int m = __builtin_amdgcn_update_dpp(0, __float_as_int(v), CTRL, 0xF, 0xF, true);
    return v + __int_as_float(m);
}
__device__ __forceinline__ float wave_sum(float v) {
    v = dpp_add<0x111>(v);   // row_shr:1
    v = dpp_add<0x112>(v);   // row_shr:2
    v = dpp_add<0x114>(v);   // row_shr:4
    v = dpp_add<0x118>(v);   // row_shr:8
    v = dpp_add<0x142>(v);   // row_bcast:15
    v = dpp_add<0x143>(v);   // row_bcast:31
    return v;                // lane 63 = full 64-lane sum
}

// branchless atan2 in [0, 2*pi): poly A&S 4.4.49, |err| <= 1e-5 rad
__device__ __forceinline__ float atan2_2pi(float y, float x) {
    const float ax = fabsf(x), ay = fabsf(y);
    const float mx = fmaxf(ax, ay), mn = fminf(ax, ay);
    const float t  = mn * __builtin_amdgcn_rcpf(fmaxf(mx, 1e-30f)); // (0,0) -> 0
    const float t2 = t * t;
    float a = fmaf(t2, 0.0208351f, -0.0851330f);
    a = fmaf(t2, a, 0.1801410f);
    a = fmaf(t2, a, -0.3302995f);
    a = fmaf(t2, a, 0.9998660f);
    a *= t;                                   // atan(mn/mx) in [0, pi/4]
    a = (ay > ax) ? (HALF_PI_F - a) : a;      // [0, pi/2]
    a = (x < 0.0f) ? (PI_F - a) : a;          // [0, pi]
    return (y < 0.0f) ? (TWO_PI_F - a) : a;   // [0, 2*pi)
}

struct Feat { float spd, dst, dir; int idx; };

__device__ __forceinline__ Feat features(const f4* c, float robs,
                                          float lx, float ly, float inv_step) {
    Feat f;
    const f4 v0 = c[0], v1 = c[1], v2 = c[2], v3 = c[3];
    const float msum = ((v0.x + v0.y) + (v0.z + v0.w))
                     + ((v1.x + v1.y) + (v1.z + v1.w))
                     + ((v2.x + v2.y) + (v2.z + v2.w))
                     + ((v3.x + v3.y) + (v3.z + v3.w));
    const float ex = v3.z, ey = v3.w;                 // t=7
    const float nvx = ex - v0.x, nvy = ey - v0.y;     // t7 - t0
    f.spd = (__builtin_amdgcn_sqrtf(fmaf(nvx, nvx, nvy * nvy)) + MU) * robs;
    const float px = ex - lx, py = ey - ly;
    f.dst = __builtin_amdgcn_sqrtf(fmaf(px, px, py * py));
    f.dir = atan2_2pi(py, px);
    const int idx = (int)(f.dir * inv_step);          // dir in [0,2pi) -> idx >= 0
    // msum==0 -> invalid; idx==P (dir rounded to 2*pi) matches one_hot OOR: excluded
    f.idx = ((msum != 0.0f) && (idx < P)) ? idx : -1;
    return f;
}

__global__ __launch_bounds__(256, 8) void social_circle_kernel(
    const float* __restrict__ trajs,   // [B, 8, 2]
    const float* __restrict__ nei,     // [B, 128, 8, 2]
    float* __restrict__ social,        // [B, P, 3]
    float* __restrict__ fdir,          // [B, N]
    int B)
{
    const int lane = threadIdx.x & 63;
    const int wib  = threadIdx.x >> 6;
    const size_t b = (size_t)blockIdx.x * WPB + wib;   // one row per wave
    if (b >= (size_t)B) return;

    const float inv_step = 1.0f / (TWO_PI_F / (float)P);

    // 8x dwordx4 nontemporal (streaming, zero reuse): lane owns neighbors
    // lane and lane+64 (64B each)
    const f4* base = (const f4*)(nei + b * (N * 16));
    f4 c0[4], c1[4];
    #pragma unroll
    for (int k = 0; k < 4; ++k) c0[k] = ldnt(base + lane * 4 + k);
    #pragma unroll
    for (int k = 0; k < 4; ++k) c1[k] = ldnt(base + (lane + 64) * 4 + k);

    // trajs row: wave-uniform -> scalar loads
    const float* tb = trajs + b * 16;
    const float lx = tb[14], ly = tb[15];
    const float ox = lx - tb[0], oy = ly - tb[1];
    const float robs = __builtin_amdgcn_rcpf(
        __builtin_amdgcn_sqrtf(fmaf(ox, ox, oy * oy)) + MU);

    const Feat f0 = features(c0, robs, lx, ly, inv_step);   // neighbor lane
    const Feat f1 = features(c1, robs, lx, ly, inv_step);   // neighbor lane+64

    // coalesced write-once f_direction stores (nontemporal)
    __builtin_nontemporal_store(f0.dir, fdir + b * N + lane);
    __builtin_nontemporal_store(f1.dir, fdir + b * N + 64 + lane);

    // per-bucket sums on the VALU pipe (DPP) + scalar counts (ballot/popc).
    // No LDS, no atomics, no barriers.
    f4 o[6];   // 24 outputs [p][f]; only lane 63's values matter
    #pragma unroll
    for (int p = 0; p < P; ++p) {
        const bool m0 = (f0.idx == p);
        const bool m1 = (f1.idx == p);
        const int cnt = __popcll(__ballot(m0)) + __popcll(__ballot(m1));
        const float rc = __builtin_amdgcn_rcpf((float)cnt + COUNT_EPS);
        const float s_spd = wave_sum((m0 ? f0.spd : 0.0f) + (m1 ? f1.spd : 0.0f));
        const float s_dst = wave_sum((m0 ? f0.dst : 0.0f) + (m1 ? f1.dst : 0.0f));
        const float s_dir = wave_sum((m0 ? f0.dir : 0.0f) + (m1 ? f1.dir : 0.0f));
        const int k = p * 3;
        ((float*)o)[k + 0] = s_spd * rc;
        ((float*)o)[k + 1] = s_dst * rc;
        ((float*)o)[k + 2] = s_dir * rc;
    }

    if (lane == 63) {
        f4* sp = (f4*)(social + b * (P * 3));   // 96B, 16B-aligned
        #pragma unroll
        for (int j = 0; j < 6; ++j) sp[j] = o[j];
    }
}

extern "C" void kernel_launch(void* const* d_in, const int* in_sizes, int n_in,
                              void* d_out, int out_size, void* d_ws, size_t ws_size,
                              hipStream_t stream) {
    const float* trajs = (const float*)d_in[0];
    const float* nei   = (const float*)d_in[1];
    const int B = in_sizes[0] / 16;  // trajs is [B, 8, 2]

    float* social = (float*)d_out;                       // [B, 8, 3]
    float* fdir   = (float*)d_out + (size_t)B * P * 3;   // [B, 128]

    const int blocks = (B + WPB - 1) / WPB;
    social_circle_kernel<<<blocks, WPB * 64, 0, stream>>>(trajs, nei, social, fdir, B);
}

// Round 12
// 17.777 us; speedup vs baseline: 1.4207x; 1.4207x over previous
//
#include <hip/hip_runtime.h>
#include <math.h>

#define MU 1e-4f
#define COUNT_EPS 1e-4f
#define TWO_PI_F 6.28318530717958647692f
#define PI_F 3.14159265358979323846f
#define HALF_PI_F 1.57079632679489661923f

constexpr int P   = 8;    // partitions (reference fixes 8)
constexpr int N   = 128;  // neighbors
constexpr int WPB = 4;    // waves per block; 1 row per wave (max TLP)

// ---- DPP wave-64 sum: result valid in lane 63 (rocPRIM idiom) ----
template <int CTRL>
__device__ __forceinline__ float dpp_add(float v) {
    int m = __builtin_amdgcn_update_dpp(0, __float_as_int(v), CTRL, 0xF, 0xF, true);
    return v + __int_as_float(m);
}
__device__ __forceinline__ float wave_sum(float v) {
    v = dpp_add<0x111>(v);   // row_shr:1
    v = dpp_add<0x112>(v);   // row_shr:2
    v = dpp_add<0x114>(v);   // row_shr:4
    v = dpp_add<0x118>(v);   // row_shr:8
    v = dpp_add<0x142>(v);   // row_bcast:15
    v = dpp_add<0x143>(v);   // row_bcast:31
    return v;                // lane 63 = full 64-lane sum
}

// branchless atan2 in [0, 2*pi): poly A&S 4.4.49, |err| <= 1e-5 rad
__device__ __forceinline__ float atan2_2pi(float y, float x) {
    const float ax = fabsf(x), ay = fabsf(y);
    const float mx = fmaxf(ax, ay), mn = fminf(ax, ay);
    const float t  = mn * __builtin_amdgcn_rcpf(fmaxf(mx, 1e-30f)); // (0,0) -> 0
    const float t2 = t * t;
    float a = fmaf(t2, 0.0208351f, -0.0851330f);
    a = fmaf(t2, a, 0.1801410f);
    a = fmaf(t2, a, -0.3302995f);
    a = fmaf(t2, a, 0.9998660f);
    a *= t;                                   // atan(mn/mx) in [0, pi/4]
    a = (ay > ax) ? (HALF_PI_F - a) : a;      // [0, pi/2]
    a = (x < 0.0f) ? (PI_F - a) : a;          // [0, pi]
    return (y < 0.0f) ? (TWO_PI_F - a) : a;   // [0, 2*pi)
}

struct Feat { float spd, dst, dir; int idx; };

__device__ __forceinline__ Feat features(const float4* c, float robs,
                                          float lx, float ly, float inv_step) {
    Feat f;
    const float4 v0 = c[0], v1 = c[1], v2 = c[2], v3 = c[3];
    const float msum = ((v0.x + v0.y) + (v0.z + v0.w))
                     + ((v1.x + v1.y) + (v1.z + v1.w))
                     + ((v2.x + v2.y) + (v2.z + v2.w))
                     + ((v3.x + v3.y) + (v3.z + v3.w));
    const float ex = v3.z, ey = v3.w;                 // t=7
    const float nvx = ex - v0.x, nvy = ey - v0.y;     // t7 - t0
    f.spd = (__builtin_amdgcn_sqrtf(fmaf(nvx, nvx, nvy * nvy)) + MU) * robs;
    const float px = ex - lx, py = ey - ly;
    f.dst = __builtin_amdgcn_sqrtf(fmaf(px, px, py * py));
    f.dir = atan2_2pi(py, px);
    const int idx = (int)(f.dir * inv_step);
    // msum==0 -> invalid; idx==P (dir rounded to 2*pi) matches one_hot OOR: excluded
    f.idx = ((msum != 0.0f) && (idx < P)) ? idx : -1;
    return f;
}

__global__ __launch_bounds__(256) void social_circle_kernel(
    const float* __restrict__ trajs,   // [B, 8, 2]
    const float* __restrict__ nei,     // [B, 128, 8, 2]
    float* __restrict__ social,        // [B, P, 3]
    float* __restrict__ fdir,          // [B, N]
    int B)
{
    const int lane = threadIdx.x & 63;
    const int wib  = threadIdx.x >> 6;
    const size_t b = (size_t)blockIdx.x * WPB + wib;   // one row per wave
    if (b >= (size_t)B) return;

    const float inv_step = 1.0f / (TWO_PI_F / (float)P);

    // 8x dwordx4 in flight; lane handles neighbors n0=lane, n1=lane+64
    const float4* base = (const float4*)(nei + b * (N * 16));
    float4 c0[4], c1[4];
    #pragma unroll
    for (int k = 0; k < 4; ++k) c0[k] = base[lane * 4 + k];
    #pragma unroll
    for (int k = 0; k < 4; ++k) c1[k] = base[(lane + 64) * 4 + k];

    // trajs row: wave-uniform -> scalar loads
    const float* tb = trajs + b * 16;
    const float lx = tb[14], ly = tb[15];
    const float ox = lx - tb[0], oy = ly - tb[1];
    const float robs = __builtin_amdgcn_rcpf(
        __builtin_amdgcn_sqrtf(fmaf(ox, ox, oy * oy)) + MU);

    const Feat f0 = features(c0, robs, lx, ly, inv_step);   // neighbor lane
    const Feat f1 = features(c1, robs, lx, ly, inv_step);   // neighbor lane+64

    // coalesced f_direction stores (two contiguous 256B wave stores)
    fdir[b * N + lane]      = f0.dir;
    fdir[b * N + 64 + lane] = f1.dir;

    // per-bucket sums on the VALU pipe (DPP) + scalar counts (ballot/popc).
    // No LDS, no DS atomics, no barriers.
    float4 o[6];   // 24 outputs [p][f]; only lane 63's values are meaningful
    #pragma unroll
    for (int p = 0; p < P; ++p) {
        const bool m0 = (f0.idx == p);
        const bool m1 = (f1.idx == p);
        const int cnt = __popcll(__ballot(m0)) + __popcll(__ballot(m1));
        const float rc = __builtin_amdgcn_rcpf((float)cnt + COUNT_EPS);
        const float s_spd = wave_sum((m0 ? f0.spd : 0.0f) + (m1 ? f1.spd : 0.0f));
        const float s_dst = wave_sum((m0 ? f0.dst : 0.0f) + (m1 ? f1.dst : 0.0f));
        const float s_dir = wave_sum((m0 ? f0.dir : 0.0f) + (m1 ? f1.dir : 0.0f));
        const int k = p * 3;
        ((float*)o)[k + 0] = s_spd * rc;
        ((float*)o)[k + 1] = s_dst * rc;
        ((float*)o)[k + 2] = s_dir * rc;
    }

    if (lane == 63) {
        float4* sp = (float4*)(social + b * (P * 3));   // 96B, 16B-aligned
        #pragma unroll
        for (int j = 0; j < 6; ++j) sp[j] = o[j];
    }
}

extern "C" void kernel_launch(void* const* d_in, const int* in_sizes, int n_in,
                              void* d_out, int out_size, void* d_ws, size_t ws_size,
                              hipStream_t stream) {
    const float* trajs = (const float*)d_in[0];
    const float* nei   = (const float*)d_in[1];
    const int B = in_sizes[0] / 16;  // trajs is [B, 8, 2]

    float* social = (float*)d_out;                       // [B, 8, 3]
    float* fdir   = (float*)d_out + (size_t)B * P * 3;   // [B, 128]

    const int blocks = (B + WPB - 1) / WPB;
    social_circle_kernel<<<blocks, WPB * 64, 0, stream>>>(trajs, nei, social, fdir, B);
}